// Round 1
// baseline (18740.659 us; speedup 1.0000x reference)
//
#include <hip/hip_runtime.h>
#include <hip/hip_bf16.h>

#define BB 2
#define LL 2048
#define DS 128
#define DF 1024
#define NH 4
#define NP 3
#define VV 32000
#define FFH 4096   // FFN_MULT*DF
#define CTXD 2048  // 2*DF

// ---------------- GEMM ----------------
// C[M,N] = beta*C + epi(A @ op(B) + bias)
// A: [M,K] row-major (lda). BT=true: B [N,K] row-major (ldb). BT=false: B [K,N] (ldb).
// TRI=true: skip k-tiles with k0 >= m0+BM (causal render; upper region of A is zero-filled).
// Batched over blockIdx.z with strides sA/sB/sC (elements).
enum { EPI_NONE=0, EPI_TANH=1, EPI_GELU=2, EPI_EXPM=3 };

#define BM 128
#define BN 128
#define BK 8

template<int EPI, bool BETA, bool BT, bool TRI>
__global__ __launch_bounds__(256) void gemm_f32(
    const float* __restrict__ A, int lda, long sA,
    const float* __restrict__ B, int ldb, long sB,
    float* __restrict__ C, int ldc, long sC,
    int M, int N, int K,
    const float* __restrict__ bias,
    const float* __restrict__ m2s, long sM2,
    const float* __restrict__ log_tau)
{
    __shared__ __align__(16) float As[BK][BM];
    __shared__ __align__(16) float Bs[BK][BN];
    int z = blockIdx.z;
    A += (long)z * sA; B += (long)z * sB; C += (long)z * sC;
    const float* m2p = (EPI == EPI_EXPM) ? (m2s + (long)z * sM2) : nullptr;

    int m0 = blockIdx.y * BM;
    int n0 = blockIdx.x * BN;
    int tid = threadIdx.x;
    int tx = tid & 15, ty = tid >> 4;

    float acc[8][8];
    #pragma unroll
    for (int i = 0; i < 8; i++)
        #pragma unroll
        for (int j = 0; j < 8; j++) acc[i][j] = 0.f;

    int kEnd = K;
    if (TRI) { int km = m0 + BM; kEnd = km < K ? km : K; }

    int arow = tid >> 1, akk = (tid & 1) * 4;   // A/B(NT) staging: 2 threads/row, float4 along K
    for (int k0 = 0; k0 < kEnd; k0 += BK) {
        float4 av = *(const float4*)(A + (long)(m0 + arow) * lda + k0 + akk);
        As[akk+0][arow] = av.x; As[akk+1][arow] = av.y;
        As[akk+2][arow] = av.z; As[akk+3][arow] = av.w;
        if (BT) {
            float4 bv = *(const float4*)(B + (long)(n0 + arow) * ldb + k0 + akk);
            Bs[akk+0][arow] = bv.x; Bs[akk+1][arow] = bv.y;
            Bs[akk+2][arow] = bv.z; Bs[akk+3][arow] = bv.w;
        } else {
            int brow = tid >> 5, bcol = (tid & 31) * 4;
            float4 bv = *(const float4*)(B + (long)(k0 + brow) * ldb + n0 + bcol);
            *(float4*)&Bs[brow][bcol] = bv;
        }
        __syncthreads();
        #pragma unroll
        for (int kk = 0; kk < BK; kk++) {
            float a[8], b[8];
            *(float4*)&a[0] = *(const float4*)&As[kk][ty*8];
            *(float4*)&a[4] = *(const float4*)&As[kk][ty*8+4];
            *(float4*)&b[0] = *(const float4*)&Bs[kk][tx*8];
            *(float4*)&b[4] = *(const float4*)&Bs[kk][tx*8+4];
            #pragma unroll
            for (int i = 0; i < 8; i++)
                #pragma unroll
                for (int j = 0; j < 8; j++)
                    acc[i][j] = fmaf(a[i], b[j], acc[i][j]);
        }
        __syncthreads();
    }

    float scale = 0.f;
    if (EPI == EPI_EXPM) scale = -0.5f * expf(-log_tau[0]);

    #pragma unroll
    for (int i = 0; i < 8; i++) {
        int row = m0 + ty*8 + i;
        float* cp = C + (long)row * ldc + n0 + tx*8;
        float out[8];
        #pragma unroll
        for (int j = 0; j < 8; j++) {
            float v = acc[i][j];
            int col = n0 + tx*8 + j;
            if (EPI == EPI_EXPM) {
                v = expf(scale * (v + m2p[col]));
            } else {
                if (bias) v += bias[col];
                if (EPI == EPI_TANH) v = tanhf(v);
                else if (EPI == EPI_GELU) v = 0.5f*v*(1.f + erff(v*0.70710678118654752f));
            }
            out[j] = v;
        }
        if (BETA) {
            float4 c0 = *(const float4*)(cp);
            float4 c1 = *(const float4*)(cp + 4);
            out[0]+=c0.x; out[1]+=c0.y; out[2]+=c0.z; out[3]+=c0.w;
            out[4]+=c1.x; out[5]+=c1.y; out[6]+=c1.z; out[7]+=c1.w;
        }
        *(float4*)cp       = make_float4(out[0],out[1],out[2],out[3]);
        *(float4*)(cp + 4) = make_float4(out[4],out[5],out[6],out[7]);
    }
}

// ---------------- embed ----------------
__global__ __launch_bounds__(256) void embed_kernel(
    const int* __restrict__ ids, const float* __restrict__ tok_mu,
    const float* __restrict__ tok_lv, const float* __restrict__ tok_ra,
    const float* __restrict__ tok_f, const float* __restrict__ pos_mu,
    float* __restrict__ mu, float* __restrict__ iv,
    float* __restrict__ alpha, float* __restrict__ feat)
{
    int r = blockIdx.x; int l = r % LL;
    int id = ids[r];
    int tid = threadIdx.x;
    for (int i = tid; i < DS; i += 256) {
        mu[(long)r*DS + i] = tok_mu[(long)id*DS + i] + pos_mu[(long)l*DS + i];
        iv[(long)r*DS + i] = expf(-tok_lv[(long)id*DS + i]);
    }
    for (int i = tid; i < DF; i += 256)
        feat[(long)r*DF + i] = tok_f[(long)id*DF + i];
    if (tid == 0) alpha[r] = 1.f/(1.f + expf(-tok_ra[id]));
}

// Q operand: [iv, mu*iv] per row; m2s = sum(mu^2*iv)
__global__ __launch_bounds__(128) void qbuild_kernel(
    const float* __restrict__ mu, const float* __restrict__ iv,
    float* __restrict__ Q, float* __restrict__ m2s)
{
    int r = blockIdx.x; int d = threadIdx.x;
    float ivd = iv[(long)r*DS + d];
    float m   = mu[(long)r*DS + d];
    Q[(long)r*256 + d]       = ivd;
    Q[(long)r*256 + 128 + d] = m * ivd;
    __shared__ float red[128];
    red[d] = m*m*ivd; __syncthreads();
    for (int s = 64; s > 0; s >>= 1) { if (d < s) red[d] += red[d+s]; __syncthreads(); }
    if (d == 0) m2s[r] = red[0];
}

// P operand: [q^2, -2q] per row
__global__ __launch_bounds__(128) void pbuild_kernel(const float* __restrict__ q, float* __restrict__ P)
{
    int r = blockIdx.x; int d = threadIdx.x;
    float qv = q[(long)r*DS + d];
    P[(long)r*256 + d]       = qv*qv;
    P[(long)r*256 + 128 + d] = -2.f*qv;
}

// stick-breaking weights: W[t,j] = eff[j] * prod_{j'<j}(1-eff[j']), eff = min(alpha_j*K[t,j], 1-1e-6) for j<=t
__global__ __launch_bounds__(256) void scan_weights(float* __restrict__ Kmat, const float* __restrict__ alpha)
{
    int r = blockIdx.x;              // b*L + t
    int b = r / LL, t = r % LL;
    float* row = Kmat + (long)r * LL;
    const float* al = alpha + (long)b * LL;
    int tid = threadIdx.x;
    int lane = tid & 63, wid = tid >> 6;
    __shared__ float wtot[4];
    float carry = 1.f;
    for (int j0 = 0; j0 < LL; j0 += 256) {
        int j = j0 + tid;
        if (j0 > t) { row[j] = 0.f; continue; }   // block-uniform branch
        float eff = 0.f;
        if (j <= t) eff = fminf(al[j] * row[j], 1.f - 1e-6f);
        float om = 1.f - eff;
        float incl = om;
        #pragma unroll
        for (int d = 1; d < 64; d <<= 1) {
            float v = __shfl_up(incl, d);
            if (lane >= d) incl *= v;
        }
        if (lane == 63) wtot[wid] = incl;
        float excl = __shfl_up(incl, 1);
        if (lane == 0) excl = 1.f;
        __syncthreads();
        float wpre = carry;
        for (int w = 0; w < wid; w++) wpre *= wtot[w];
        row[j] = eff * wpre * excl;
        float tot = wtot[0]*wtot[1]*wtot[2]*wtot[3];
        __syncthreads();
        carry *= tot;
    }
}

// row layernorm
template<int C>
__global__ __launch_bounds__(256) void ln_kernel(
    const float* __restrict__ x, const float* __restrict__ g,
    const float* __restrict__ b, float* __restrict__ y)
{
    int r = blockIdx.x;
    const float* xr = x + (long)r*C;
    __shared__ float xs[C];
    __shared__ float red[256];
    int tid = threadIdx.x;
    float s = 0.f;
    for (int i = tid; i < C; i += 256) { float v = xr[i]; xs[i] = v; s += v; }
    red[tid] = s; __syncthreads();
    for (int st = 128; st > 0; st >>= 1) { if (tid < st) red[tid] += red[tid+st]; __syncthreads(); }
    float mean = red[0] / C;
    __syncthreads();
    float s2 = 0.f;
    for (int i = tid; i < C; i += 256) { float d = xs[i]-mean; s2 += d*d; }
    red[tid] = s2; __syncthreads();
    for (int st = 128; st > 0; st >>= 1) { if (tid < st) red[tid] += red[tid+st]; __syncthreads(); }
    float rs = rsqrtf(red[0]/C + 1e-5f);
    for (int i = tid; i < C; i += 256) y[(long)r*C + i] = (xs[i]-mean)*rs*g[i] + b[i];
}

// alpha *= sigmoid(ctx . ag_w + ag_b)
__global__ __launch_bounds__(256) void alpha_kernel(
    const float* __restrict__ ctx, const float* __restrict__ agw,
    const float* __restrict__ agb, float* __restrict__ alpha)
{
    int r = blockIdx.x;
    const float* xr = ctx + (long)r*CTXD;
    __shared__ float red[256];
    int tid = threadIdx.x;
    float s = 0.f;
    for (int i = tid; i < CTXD; i += 256) s += xr[i]*agw[i];
    red[tid] = s; __syncthreads();
    for (int st = 128; st > 0; st >>= 1) { if (tid < st) red[tid] += red[tid+st]; __syncthreads(); }
    if (tid == 0) alpha[r] *= 1.f/(1.f + expf(-(red[0] + agb[0])));
}

// ctx = [features, meaning]
__global__ __launch_bounds__(256) void ctx_kernel(
    const float* __restrict__ feat, const float* __restrict__ meaning, float* __restrict__ ctx)
{
    long i4 = (long)blockIdx.x * 256 + threadIdx.x;   // float4 index, 512 per row
    long r = i4 >> 9;
    long c4 = i4 & 511;
    const float4* src = (c4 < 256) ? (const float4*)(feat + r*DF) + c4
                                   : (const float4*)(meaning + r*DF) + (c4 - 256);
    ((float4*)ctx)[i4] = *src;
}

extern "C" void kernel_launch(void* const* d_in, const int* in_sizes, int n_in,
                              void* d_out, int out_size, void* d_ws, size_t ws_size,
                              hipStream_t stream)
{
    const int*   token_ids = (const int*)d_in[0];
    const float* tok_mu  = (const float*)d_in[1];
    const float* tok_lv  = (const float*)d_in[2];
    const float* tok_ra  = (const float*)d_in[3];
    const float* tok_f   = (const float*)d_in[4];
    const float* pos_mu  = (const float*)d_in[5];
    const float* log_tau = (const float*)d_in[6];
    const float* qp_w = (const float*)d_in[7];
    const float* qp_b = (const float*)d_in[8];
    const float* hp_w = (const float*)d_in[9];
    const float* hp_b = (const float*)d_in[10];
    const float* mu_w = (const float*)d_in[11];
    const float* mu_b = (const float*)d_in[12];
    const float* ag_w = (const float*)d_in[13];
    const float* ag_b = (const float*)d_in[14];
    const float* ln_g = (const float*)d_in[15];
    const float* ln_b = (const float*)d_in[16];
    const float* w1 = (const float*)d_in[17];
    const float* b1 = (const float*)d_in[18];
    const float* w2 = (const float*)d_in[19];
    const float* b2 = (const float*)d_in[20];
    const float* lnf_g = (const float*)d_in[21];
    const float* lnf_b = (const float*)d_in[22];
    const float* lm_w  = (const float*)d_in[23];
    float* out = (float*)d_out;

    // workspace layout (floats) — total 33,038,336 floats = 132.2 MB
    float* ws      = (float*)d_ws;
    float* mu      = ws;                     // 524288
    float* iv      = mu + 524288;            // 524288
    float* alpha   = iv + 524288;            // 4096
    float* m2s     = alpha + 4096;           // 4096
    float* q       = m2s + 4096;             // 524288
    float* P       = q + 524288;             // 1048576  [B,L,256]
    float* Q       = P + 1048576;            // 1048576  [B,L,256]
    float* feat    = Q + 1048576;            // 4194304  [B,L,DF]
    float* meaning = feat + 4194304;         // 4194304
    float* head_m  = meaning + 4194304;      // 4194304
    float* ctx     = head_m + 4194304;       // 8388608  [B,L,2DF]
    float* Kbuf    = ctx + 8388608;          // 8388608  [B,L,L]
    float* h1  = Kbuf;      // alias: LN(ctx), used after heads done
    float* h2  = head_m;    // alias: FFN hidden, 1024-row chunks
    float* lnm = head_m;    // alias: final LN output

    const int R = BB * LL;  // 4096

    embed_kernel<<<R, 256, 0, stream>>>(token_ids, tok_mu, tok_lv, tok_ra, tok_f, pos_mu,
                                        mu, iv, alpha, feat);

    for (int p = 0; p < NP; p++) {
        qbuild_kernel<<<R, 128, 0, stream>>>(mu, iv, Q, m2s);
        for (int h = 0; h < NH; h++) {
            // q = mu @ qp_w[h]^T + qp_b[h]
            dim3 g1(DS/BN, R/BM, 1);
            gemm_f32<EPI_NONE,false,true,false><<<g1,256,0,stream>>>(
                mu, DS, 0, qp_w + (long)h*DS*DS, DS, 0, q, DS, 0,
                R, DS, DS, qp_b + h*DS, nullptr, 0, nullptr);
            pbuild_kernel<<<R, 128, 0, stream>>>(q, P);
            // K = exp(-0.5*(P@Q^T + m2s[j])/tau), batched over b
            dim3 g2(LL/BN, LL/BM, BB);
            gemm_f32<EPI_EXPM,false,true,false><<<g2,256,0,stream>>>(
                P, 256, (long)LL*256, Q, 256, (long)LL*256, Kbuf, LL, (long)LL*LL,
                LL, LL, 256, nullptr, m2s, LL, log_tau);
            // stick-breaking weights in place
            scan_weights<<<R, 256, 0, stream>>>(Kbuf, alpha);
            // head_m = W @ features  (NN, causal k-skip)
            dim3 g3(DF/BN, LL/BM, BB);
            gemm_f32<EPI_NONE,false,false,true><<<g3,256,0,stream>>>(
                Kbuf, LL, (long)LL*LL, feat, DF, (long)LL*DF, head_m, DF, (long)LL*DF,
                LL, DF, LL, nullptr, nullptr, 0, nullptr);
            // meaning (+)= head_m @ hp_w[:, h*DF:(h+1)*DF]^T  (+ hp_b at h==0)
            dim3 g4(DF/BN, R/BM, 1);
            if (h == 0)
                gemm_f32<EPI_NONE,false,true,false><<<g4,256,0,stream>>>(
                    head_m, DF, 0, hp_w + (long)h*DF, NH*DF, 0, meaning, DF, 0,
                    R, DF, DF, hp_b, nullptr, 0, nullptr);
            else
                gemm_f32<EPI_NONE,true,true,false><<<g4,256,0,stream>>>(
                    head_m, DF, 0, hp_w + (long)h*DF, NH*DF, 0, meaning, DF, 0,
                    R, DF, DF, nullptr, nullptr, 0, nullptr);
        }
        if (p < NP - 1) {
            ctx_kernel<<<(R*CTXD/4)/256, 256, 0, stream>>>(feat, meaning, ctx);
            // mu += tanh(ctx @ mu_w[p]^T + mu_b[p])
            dim3 g5(DS/BN, R/BM, 1);
            gemm_f32<EPI_TANH,true,true,false><<<g5,256,0,stream>>>(
                ctx, CTXD, 0, mu_w + (long)p*DS*CTXD, CTXD, 0, mu, DS, 0,
                R, DS, CTXD, mu_b + p*DS, nullptr, 0, nullptr);
            alpha_kernel<<<R, 256, 0, stream>>>(ctx, ag_w + (long)p*CTXD, ag_b + p, alpha);
            ln_kernel<CTXD><<<R, 256, 0, stream>>>(ctx, ln_g + (long)p*CTXD, ln_b + (long)p*CTXD, h1);
            // FFN in 1024-row chunks (h2 aliases head_m)
            for (int c = 0; c < 4; c++) {
                long ro = (long)c * 1024;
                dim3 g6(FFH/BN, 1024/BM, 1);
                gemm_f32<EPI_GELU,false,true,false><<<g6,256,0,stream>>>(
                    h1 + ro*CTXD, CTXD, 0, w1 + (long)p*FFH*CTXD, CTXD, 0, h2, FFH, 0,
                    1024, FFH, CTXD, b1 + (long)p*FFH, nullptr, 0, nullptr);
                dim3 g7(DF/BN, 1024/BM, 1);
                gemm_f32<EPI_NONE,true,true,false><<<g7,256,0,stream>>>(
                    h2, FFH, 0, w2 + (long)p*DF*FFH, FFH, 0, feat + ro*DF, DF, 0,
                    1024, DF, FFH, b2 + (long)p*DF, nullptr, 0, nullptr);
            }
        }
    }

    // logits = LN(meaning) @ lm_w^T
    ln_kernel<DF><<<R, 256, 0, stream>>>(meaning, lnf_g, lnf_b, lnm);
    dim3 g8(VV/BN, R/BM, 1);
    gemm_f32<EPI_NONE,false,true,false><<<g8,256,0,stream>>>(
        lnm, DF, 0, lm_w, DF, 0, out, VV, 0,
        R, VV, DF, nullptr, nullptr, 0, nullptr);
}